// Round 5
// baseline (5906.364 us; speedup 1.0000x reference)
//
#include <hip/hip_runtime.h>

// EagerRNN: B=64, T=512, F=512, H=1024.
// xproj = x @ W[:512] + b  (32768x1024x512 GEMM)
// scan:  state = tanh(xproj[:,t,:] + state @ W[512:])   512 sequential steps
// out: final state (64,1024) f32.
//
// Phase 2: persistent 64-block kernel, 4 groups x 16 slices, BARRIER-FREE.
// Each WAVE is an independent agent: per-wave monotonic flags (64 per
// group), agent-scope exchange through the LLC (the proven r0/r1 protocol:
// data stores -> vmcnt(0) drain -> flag store; consumers poll flags then
// load). Consumer waves read MFMA A-fragments DIRECTLY from the global
// state image (plain row-major [16][1024] f16): fragment chunk for MFMA kk
// is row*2048 + kk*64 + sub*16 == exactly the bytes the old LDS path
// delivered. No __syncthreads in the step loop, no LDS state tile, no
// block-level jitter coupling. Wh slice register-resident (32 x f16x8).
// Overwrite safety (wave granularity): a wave stores parity(t+1) only after
// seeing all 64 producer-wave flags >= t; each flag publishes only after
// that wave's vmcnt(0), which drains its parity(t-1)==(t+1) reads.

typedef _Float16 f16;
typedef _Float16 f16x8 __attribute__((ext_vector_type(8)));
typedef _Float16 f16x4 __attribute__((ext_vector_type(4)));
typedef float f32x4 __attribute__((ext_vector_type(4)));
typedef unsigned long long u64;
typedef unsigned u32;
typedef unsigned long long u64x2 __attribute__((ext_vector_type(2)));

#define B_  64
#define T_  512
#define F_  512
#define H_  1024

// workspace layout (bytes)
#define XPH_OFF  0ull                         // f16 [T][B][H]  = 64 MB
#define WXT_OFF  67108864ull                  // f16 [H][F]     = 1 MB
#define WHT_OFF  68157440ull                  // f16 [H][H]     = 2 MB
#define SBUF_OFF 70254592ull                  // f16 image, 2 parities x 4 groups x 32768 B
#define BAR_OFF  70516736ull                  // 4 groups x 64 wave-flags x 4B = 1 KB (pad 2 KB)
#define WS_NEED  70518784ull

#define ALD64(p)    __hip_atomic_load((const u64*)(p), __ATOMIC_RELAXED, __HIP_MEMORY_SCOPE_AGENT)
#define AST64(p, v) __hip_atomic_store((u64*)(p), (v), __ATOMIC_RELAXED, __HIP_MEMORY_SCOPE_AGENT)
#define ALD32(p)    __hip_atomic_load((const u32*)(p), __ATOMIC_RELAXED, __HIP_MEMORY_SCOPE_AGENT)
#define AST32(p, v) __hip_atomic_store((u32*)(p), (v), __ATOMIC_RELAXED, __HIP_MEMORY_SCOPE_AGENT)

// ---------------------------------------------------------------------------
// prep: W f32 [1536][1024] -> WxT f16 [h][k<512], WhT f16 [h][k<1024]
__global__ __launch_bounds__(256) void k_prep(const float* __restrict__ W,
                                              f16* __restrict__ WxT,
                                              f16* __restrict__ WhT) {
  __shared__ float tile[32][33];
  const int tid = threadIdx.x;
  const int kt = blockIdx.x >> 5;   // 0..47 (32 k-rows each)
  const int ht = blockIdx.x & 31;   // 0..31 (32 h-cols each)
#pragma unroll
  for (int p = 0; p < 4; ++p) {
    int kr = p * 8 + (tid >> 5);
    tile[kr][tid & 31] = W[(size_t)(kt * 32 + kr) * 1024 + ht * 32 + (tid & 31)];
  }
  __syncthreads();
  const int hl = tid >> 3;   // 0..31
  const int kq = tid & 7;    // 0..7  -> 4 k each
  f16x4 v;
#pragma unroll
  for (int j = 0; j < 4; ++j) v[j] = (f16)tile[kq * 4 + j][hl];
  const int h = ht * 32 + hl;
  const int kg = kt * 32 + kq * 4;
  if (kg < 512) *(f16x4*)(WxT + (size_t)h * 512 + kg) = v;
  else          *(f16x4*)(WhT + (size_t)h * 1024 + (kg - 512)) = v;
}

// ---------------------------------------------------------------------------
// phase 1: xph[t*64+b][h] = f16( x[b][t][:] @ Wx[:][h] + bias[h] )
__global__ __launch_bounds__(256) void k_xproj(const float* __restrict__ x,
                                               const f16* __restrict__ WxT,
                                               const float* __restrict__ bias,
                                               f16* __restrict__ xph) {
  __shared__ __align__(16) unsigned char Al[65536];  // [64 m][512 k] f16, swizzled
  __shared__ __align__(16) unsigned char Bl[65536];  // [64 n][512 k] f16, swizzled
  const int tid = threadIdx.x;
  const int l = tid & 63, w = tid >> 6;
  const int lane15 = l & 15, sub = l >> 4;
  const int m0 = blockIdx.x * 64;
  const int bidx = m0 >> 9;     // batch
  const int t0 = m0 & 511;      // time base

  {
    const int r = tid >> 2, qq = tid & 3;
    const float* xs = x + (size_t)(m0 + r) * 512;
#pragma unroll
    for (int i = 0; i < 16; ++i) {
      int s = qq * 16 + i;          // 16B slot 0..63
      int c = s ^ (r & 7);          // source k-chunk (swizzle on source)
      const float4 f0 = *(const float4*)(xs + c * 8);
      const float4 f1 = *(const float4*)(xs + c * 8 + 4);
      f16x8 v;
      v[0] = (f16)f0.x; v[1] = (f16)f0.y; v[2] = (f16)f0.z; v[3] = (f16)f0.w;
      v[4] = (f16)f1.x; v[5] = (f16)f1.y; v[6] = (f16)f1.z; v[7] = (f16)f1.w;
      *(f16x8*)(Al + r * 1024 + s * 16) = v;
    }
  }

  const int mh = (w >> 1) * 32, nh = (w & 1) * 32;
  const int rA0 = mh + lane15, rA1 = mh + 16 + lane15;
  const int rB0 = nh + lane15, rB1 = nh + 16 + lane15;

  for (int nb = 0; nb < 16; ++nb) {
    const int n0 = nb * 64;
    __syncthreads();   // Bl safe to overwrite
    {
      const int r = tid >> 2, qq = tid & 3;
      const f16* bs = WxT + (size_t)(n0 + r) * 512;
#pragma unroll
      for (int i = 0; i < 16; ++i) {
        int s = qq * 16 + i;
        int c = s ^ (r & 7);
        f16x8 v = *(const f16x8*)(bs + c * 8);
        *(f16x8*)(Bl + r * 1024 + s * 16) = v;
      }
    }
    __syncthreads();
    f32x4 acc00 = {0.f,0.f,0.f,0.f}, acc01 = {0.f,0.f,0.f,0.f};
    f32x4 acc10 = {0.f,0.f,0.f,0.f}, acc11 = {0.f,0.f,0.f,0.f};
#pragma unroll
    for (int kk = 0; kk < 16; ++kk) {
      const int s = kk * 4 + sub;
      f16x8 a0 = *(const f16x8*)(Al + rA0 * 1024 + ((s ^ (rA0 & 7)) << 4));
      f16x8 a1 = *(const f16x8*)(Al + rA1 * 1024 + ((s ^ (rA1 & 7)) << 4));
      f16x8 b0 = *(const f16x8*)(Bl + rB0 * 1024 + ((s ^ (rB0 & 7)) << 4));
      f16x8 b1 = *(const f16x8*)(Bl + rB1 * 1024 + ((s ^ (rB1 & 7)) << 4));
      acc00 = __builtin_amdgcn_mfma_f32_16x16x32_f16(a0, b0, acc00, 0, 0, 0);
      acc01 = __builtin_amdgcn_mfma_f32_16x16x32_f16(a0, b1, acc01, 0, 0, 0);
      acc10 = __builtin_amdgcn_mfma_f32_16x16x32_f16(a1, b0, acc10, 0, 0, 0);
      acc11 = __builtin_amdgcn_mfma_f32_16x16x32_f16(a1, b1, acc11, 0, 0, 0);
    }
    const float bv0 = bias[n0 + nh + lane15];
    const float bv1 = bias[n0 + nh + 16 + lane15];
#pragma unroll
    for (int j = 0; j < 4; ++j) {
      const int r0 = mh + sub * 4 + j;
      const int r1 = mh + 16 + sub * 4 + j;
      const size_t row0 = (size_t)(t0 + r0) * 64 + bidx;
      const size_t row1 = (size_t)(t0 + r1) * 64 + bidx;
      xph[row0 * 1024 + n0 + nh + lane15]      = (f16)(acc00[j] + bv0);
      xph[row0 * 1024 + n0 + nh + 16 + lane15] = (f16)(acc01[j] + bv1);
      xph[row1 * 1024 + n0 + nh + lane15]      = (f16)(acc10[j] + bv0);
      xph[row1 * 1024 + n0 + nh + 16 + lane15] = (f16)(acc11[j] + bv1);
    }
  }
}

// ---------------------------------------------------------------------------
// phase 2: persistent recurrence, barrier-free per-wave dataflow.
// 64 blocks = 4 groups x 16 slices; 4 waves/block, each wave = 16 H-cols.
// State image per group per parity: plain row-major f16 [16][1024], row
// stride 2048B. Flags: u32 [4 groups][64 waves] (waveid = slice*4 + w).
__global__ __launch_bounds__(256, 1) void k_rnn(const f16* __restrict__ xph,
                                                const f16* __restrict__ WhT,
                                                f16* sbuf, unsigned* bar,
                                                float* __restrict__ out) {
  __shared__ __align__(16) unsigned char tbuf[2176];  // 16 rows x 136 B
  const int tid = threadIdx.x;
  const int l = tid & 63, w = tid >> 6;
  const int lane15 = l & 15, sub = l >> 4;
  const int bid = blockIdx.x;
  const int group = bid & 3;
  const int slice = bid >> 2;                  // 0..15

  // Wh slice in registers: breg[kk] = Wh[k = kk*32 + sub*8 .. +8][colL]
  const int colL = slice * 64 + w * 16 + lane15;
  f16x8 breg[32];
  {
    const f16* src = WhT + (size_t)colL * 1024 + sub * 8;
#pragma unroll
    for (int kk = 0; kk < 32; ++kk) breg[kk] = *(const f16x8*)(src + kk * 32);
  }
#pragma unroll
  for (int kk = 0; kk < 32; ++kk) asm volatile("" : "+v"(breg[kk]));

  unsigned* gflags = bar + group * 128;        // 64 flags, 4B each (512B/group)
  unsigned* myflag = gflags + (slice * 4 + w);
  unsigned* pollp  = gflags + l;               // lane l polls wave-flag l
  const size_t gbase = (size_t)group * 32768;

  // A-fragment base for this lane: row = lane15, k-phase = sub
  const int fragoff = lane15 * 2048 + sub * 16;
  // output store position (after wave-local transpose): row = lane15,
  // 4 cols starting at c0
  const int c0 = slice * 64 + w * 16 + sub * 4;
  const int stoff = lane15 * 2048 + c0 * 2;

  for (int t = 0; t < T_; ++t) {
    const char* ib = (const char*)sbuf + (size_t)(t & 1) * 131072 + gbase;
    char*       ob = (char*)sbuf + (size_t)((t + 1) & 1) * 131072 + gbase;

    // xp for this step (plain cached loads, issued before the poll)
    float xpv[4];
#pragma unroll
    for (int j = 0; j < 4; ++j)
      xpv[j] = (float)xph[(size_t)(t * 64 + group * 16 + sub * 4 + j) * 1024 + colL];

    // poll all 64 producer-wave flags (lane l owns flag l), wave-collective
    if (t > 0) {
      u32 fv = ALD32(pollp);
      while (!__all((int)(fv >= (u32)t))) fv = ALD32(pollp);
    }
    asm volatile("" ::: "memory");

    // load all 32 A-fragments (agent-scope 8B pairs), then MFMA
    u64 flo[32], fhi[32];
    {
      const char* rb = ib + fragoff;
#pragma unroll
      for (int kk = 0; kk < 32; ++kk) {
        flo[kk] = ALD64(rb + kk * 64);
        fhi[kk] = ALD64(rb + kk * 64 + 8);
      }
    }
    f32x4 acc0 = {0.f,0.f,0.f,0.f}, acc1 = {0.f,0.f,0.f,0.f};
    f32x4 acc2 = {0.f,0.f,0.f,0.f}, acc3 = {0.f,0.f,0.f,0.f};
#pragma unroll
    for (int kk = 0; kk < 32; kk += 4) {
      u64x2 p0; p0[0] = flo[kk + 0]; p0[1] = fhi[kk + 0];
      u64x2 p1; p1[0] = flo[kk + 1]; p1[1] = fhi[kk + 1];
      u64x2 p2; p2[0] = flo[kk + 2]; p2[1] = fhi[kk + 2];
      u64x2 p3; p3[0] = flo[kk + 3]; p3[1] = fhi[kk + 3];
      acc0 = __builtin_amdgcn_mfma_f32_16x16x32_f16(
          __builtin_bit_cast(f16x8, p0), breg[kk + 0], acc0, 0, 0, 0);
      acc1 = __builtin_amdgcn_mfma_f32_16x16x32_f16(
          __builtin_bit_cast(f16x8, p1), breg[kk + 1], acc1, 0, 0, 0);
      acc2 = __builtin_amdgcn_mfma_f32_16x16x32_f16(
          __builtin_bit_cast(f16x8, p2), breg[kk + 2], acc2, 0, 0, 0);
      acc3 = __builtin_amdgcn_mfma_f32_16x16x32_f16(
          __builtin_bit_cast(f16x8, p3), breg[kk + 3], acc3, 0, 0, 0);
    }
    float rv[4];
#pragma unroll
    for (int j = 0; j < 4; ++j)
      rv[j] = acc0[j] + acc1[j] + acc2[j] + acc3[j] + xpv[j];

    if (t == T_ - 1) {
#pragma unroll
      for (int j = 0; j < 4; ++j)
        out[(size_t)(group * 16 + sub * 4 + j) * 1024 + colL] = tanhf(rv[j]);
      break;
    }

    // wave-local transpose through tbuf (disjoint bytes per wave, no
    // barrier needed: same-wave write->read ordered by lgkmcnt)
#pragma unroll
    for (int j = 0; j < 4; ++j) {
      f16 hv = (f16)tanhf(rv[j]);
      *(f16*)(tbuf + (sub * 4 + j) * 136 + (w * 16 + lane15) * 2) = hv;
    }
    asm volatile("s_waitcnt lgkmcnt(0)" ::: "memory");
    {
      u64 packed = *(const u64*)(tbuf + lane15 * 136 + (w * 16 + sub * 4) * 2);
      AST64(ob + stoff, packed);
    }
    // drain this wave's vmem (store + all reads of parity t-1), publish flag
    asm volatile("s_waitcnt vmcnt(0)" ::: "memory");
    if (l == 0) AST32(myflag, (u32)(t + 1));
  }
}

// ---------------------------------------------------------------------------
extern "C" void kernel_launch(void* const* d_in, const int* in_sizes, int n_in,
                              void* d_out, int out_size, void* d_ws, size_t ws_size,
                              hipStream_t stream) {
  const float* x    = (const float*)d_in[0];
  const float* W    = (const float*)d_in[1];
  const float* bias = (const float*)d_in[2];
  float* out = (float*)d_out;
  char* w = (char*)d_ws;

  f16* xph = (f16*)(w + XPH_OFF);
  f16* WxT = (f16*)(w + WXT_OFF);
  f16* WhT = (f16*)(w + WHT_OFF);
  f16* sbuf = (f16*)(w + SBUF_OFF);
  unsigned* bar = (unsigned*)(w + BAR_OFF);

  // zero state image (state0 = 0, both parities) + wave flags, every launch
  hipMemsetAsync(w + SBUF_OFF, 0, 262144 + 2048, stream);

  k_prep<<<dim3(48 * 32), dim3(256), 0, stream>>>(W, WxT, WhT);
  k_xproj<<<dim3(512), dim3(256), 0, stream>>>(x, WxT, bias, xph);
  k_rnn<<<dim3(64), dim3(256), 0, stream>>>(xph, WhT, sbuf, bar, out);
}

// Round 7
// 1774.754 us; speedup vs baseline: 3.3280x; 3.3280x over previous
//
#include <hip/hip_runtime.h>

// EagerRNN: B=64, T=512, F=512, H=1024.
// xproj = x @ W[:512] + b  (32768x1024x512 GEMM)
// scan:  state = tanh(xproj[:,t,:] + state @ W[512:])   512 sequential steps
// out: final state (64,1024) f32.
//
// Phase 2: persistent 64-block kernel (r0's proven structure: 4 groups x 16
// slices, block staging -> LDS -> MFMA, Wh 8 kk in regs + 24 kk in LDS).
// EXCHANGE: flagless, drain-free, self-validating 8B words. Each aligned 8B
// state word (4 f16) carries a stolen tag bit: LSB of f16#0 = (t>>1)&1 for
// state t. 8B stores are single-copy atomic (tears only between words);
// per-location coherence + the all-validate-before-overwrite invariant
// bound slot content to {t-2, t}, which the 1-bit tag distinguishes.
// r6 HANG ROOT CAUSE (fixed here): memset gave parity-1 tag 0 == the tag
// wanted at t=1, so zeros falsely validated as state 1, breaking the skew
// invariant and deadlocking the 1-bit scheme. Fix: k_init writes parity-0
// words = 0 (tag 0 == genuine state 0) and parity-1 words = 1 (tag 1 !=
// want(t=1)=0), so only real state 1 can validate at t=1.
// Producers fire-and-forget (no vmcnt drain, no flag); consumers poll the
// data words themselves. Chain per step = store -> visible -> poll-load.

typedef _Float16 f16;
typedef _Float16 f16x8 __attribute__((ext_vector_type(8)));
typedef _Float16 f16x4 __attribute__((ext_vector_type(4)));
typedef float f32x4 __attribute__((ext_vector_type(4)));
typedef unsigned long long u64;
typedef unsigned u32;

#define B_  64
#define T_  512
#define F_  512
#define H_  1024

// workspace layout (bytes)
#define XPH_OFF  0ull                         // f16 [T][B][H]  = 64 MB
#define WXT_OFF  67108864ull                  // f16 [H][F]     = 1 MB
#define WHT_OFF  68157440ull                  // f16 [H][H]     = 2 MB
#define SBUF_OFF 70254592ull                  // f16 image, 2 parities x 4 groups x 32768 B
#define WS_NEED  70516736ull

#define ALD64(p)    __hip_atomic_load((const u64*)(p), __ATOMIC_RELAXED, __HIP_MEMORY_SCOPE_AGENT)
#define AST64(p, v) __hip_atomic_store((u64*)(p), (v), __ATOMIC_RELAXED, __HIP_MEMORY_SCOPE_AGENT)

// ---------------------------------------------------------------------------
// init: parity-0 image words = 0 (state0 = 0, tag 0), parity-1 words = 1
// (tag 1 -> cannot falsely validate at t=1, where want = 0).
__global__ __launch_bounds__(256) void k_init(u64* __restrict__ sbuf) {
  const unsigned i = blockIdx.x * 256 + threadIdx.x;   // 0..32767
  sbuf[i] = (i >= 16384) ? 1ull : 0ull;                // 16384 u64 per parity
}

// ---------------------------------------------------------------------------
// prep: W f32 [1536][1024] -> WxT f16 [h][k<512], WhT f16 [h][k<1024] (k-major
// per output column so MFMA B-fragments are contiguous 16B reads)
__global__ __launch_bounds__(256) void k_prep(const float* __restrict__ W,
                                              f16* __restrict__ WxT,
                                              f16* __restrict__ WhT) {
  __shared__ float tile[32][33];
  const int tid = threadIdx.x;
  const int kt = blockIdx.x >> 5;   // 0..47 (32 k-rows each)
  const int ht = blockIdx.x & 31;   // 0..31 (32 h-cols each)
#pragma unroll
  for (int p = 0; p < 4; ++p) {
    int kr = p * 8 + (tid >> 5);
    tile[kr][tid & 31] = W[(size_t)(kt * 32 + kr) * 1024 + ht * 32 + (tid & 31)];
  }
  __syncthreads();
  const int hl = tid >> 3;   // 0..31
  const int kq = tid & 7;    // 0..7  -> 4 k each
  f16x4 v;
#pragma unroll
  for (int j = 0; j < 4; ++j) v[j] = (f16)tile[kq * 4 + j][hl];
  const int h = ht * 32 + hl;
  const int kg = kt * 32 + kq * 4;
  if (kg < 512) *(f16x4*)(WxT + (size_t)h * 512 + kg) = v;
  else          *(f16x4*)(WhT + (size_t)h * 1024 + (kg - 512)) = v;
}

// ---------------------------------------------------------------------------
// phase 1: xph[t*64+b][h] = f16( x[b][t][:] @ Wx[:][h] + bias[h] )
__global__ __launch_bounds__(256) void k_xproj(const float* __restrict__ x,
                                               const f16* __restrict__ WxT,
                                               const float* __restrict__ bias,
                                               f16* __restrict__ xph) {
  __shared__ __align__(16) unsigned char Al[65536];  // [64 m][512 k] f16, swizzled
  __shared__ __align__(16) unsigned char Bl[65536];  // [64 n][512 k] f16, swizzled
  const int tid = threadIdx.x;
  const int l = tid & 63, w = tid >> 6;
  const int lane15 = l & 15, sub = l >> 4;
  const int m0 = blockIdx.x * 64;
  const int bidx = m0 >> 9;     // batch
  const int t0 = m0 & 511;      // time base

  {
    const int r = tid >> 2, qq = tid & 3;
    const float* xs = x + (size_t)(m0 + r) * 512;
#pragma unroll
    for (int i = 0; i < 16; ++i) {
      int s = qq * 16 + i;          // 16B slot 0..63
      int c = s ^ (r & 7);          // source k-chunk (swizzle on source)
      const float4 f0 = *(const float4*)(xs + c * 8);
      const float4 f1 = *(const float4*)(xs + c * 8 + 4);
      f16x8 v;
      v[0] = (f16)f0.x; v[1] = (f16)f0.y; v[2] = (f16)f0.z; v[3] = (f16)f0.w;
      v[4] = (f16)f1.x; v[5] = (f16)f1.y; v[6] = (f16)f1.z; v[7] = (f16)f1.w;
      *(f16x8*)(Al + r * 1024 + s * 16) = v;
    }
  }

  const int mh = (w >> 1) * 32, nh = (w & 1) * 32;
  const int rA0 = mh + lane15, rA1 = mh + 16 + lane15;
  const int rB0 = nh + lane15, rB1 = nh + 16 + lane15;

  for (int nb = 0; nb < 16; ++nb) {
    const int n0 = nb * 64;
    __syncthreads();   // Bl safe to overwrite
    {
      const int r = tid >> 2, qq = tid & 3;
      const f16* bs = WxT + (size_t)(n0 + r) * 512;
#pragma unroll
      for (int i = 0; i < 16; ++i) {
        int s = qq * 16 + i;
        int c = s ^ (r & 7);
        f16x8 v = *(const f16x8*)(bs + c * 8);
        *(f16x8*)(Bl + r * 1024 + s * 16) = v;
      }
    }
    __syncthreads();
    f32x4 acc00 = {0.f,0.f,0.f,0.f}, acc01 = {0.f,0.f,0.f,0.f};
    f32x4 acc10 = {0.f,0.f,0.f,0.f}, acc11 = {0.f,0.f,0.f,0.f};
#pragma unroll
    for (int kk = 0; kk < 16; ++kk) {
      const int s = kk * 4 + sub;
      f16x8 a0 = *(const f16x8*)(Al + rA0 * 1024 + ((s ^ (rA0 & 7)) << 4));
      f16x8 a1 = *(const f16x8*)(Al + rA1 * 1024 + ((s ^ (rA1 & 7)) << 4));
      f16x8 b0 = *(const f16x8*)(Bl + rB0 * 1024 + ((s ^ (rB0 & 7)) << 4));
      f16x8 b1 = *(const f16x8*)(Bl + rB1 * 1024 + ((s ^ (rB1 & 7)) << 4));
      acc00 = __builtin_amdgcn_mfma_f32_16x16x32_f16(a0, b0, acc00, 0, 0, 0);
      acc01 = __builtin_amdgcn_mfma_f32_16x16x32_f16(a0, b1, acc01, 0, 0, 0);
      acc10 = __builtin_amdgcn_mfma_f32_16x16x32_f16(a1, b0, acc10, 0, 0, 0);
      acc11 = __builtin_amdgcn_mfma_f32_16x16x32_f16(a1, b1, acc11, 0, 0, 0);
    }
    const float bv0 = bias[n0 + nh + lane15];
    const float bv1 = bias[n0 + nh + 16 + lane15];
#pragma unroll
    for (int j = 0; j < 4; ++j) {
      const int r0 = mh + sub * 4 + j;
      const int r1 = mh + 16 + sub * 4 + j;
      const size_t row0 = (size_t)(t0 + r0) * 64 + bidx;
      const size_t row1 = (size_t)(t0 + r1) * 64 + bidx;
      xph[row0 * 1024 + n0 + nh + lane15]      = (f16)(acc00[j] + bv0);
      xph[row0 * 1024 + n0 + nh + 16 + lane15] = (f16)(acc01[j] + bv1);
      xph[row1 * 1024 + n0 + nh + lane15]      = (f16)(acc10[j] + bv0);
      xph[row1 * 1024 + n0 + nh + 16 + lane15] = (f16)(acc11[j] + bv1);
    }
  }
}

// ---------------------------------------------------------------------------
// phase 2: persistent recurrence. 64 blocks = 4 groups (16 batch rows) x 16
// slices (64 H-cols). Wh slice: kk 0..7 in regs, kk 8..31 in LDS (96 KB);
// state tile staged to LDS (32 KB) each step via tag-polled 8B words.
__global__ __launch_bounds__(256, 1) void k_rnn(const f16* __restrict__ xph,
                                                const f16* __restrict__ WhT,
                                                f16* sbuf,
                                                float* __restrict__ out) {
  __shared__ __align__(16) unsigned char lds[131072 + 2176];
  unsigned char* WhL  = lds;            // 64 rows x 1536 B  (kslot 32..127)
  unsigned char* stL  = lds + 98304;    // 16 rows x 2048 B  (swizzled image)
  unsigned char* tbuf = lds + 131072;   // 16 rows x 136 B   (wave transpose)
  const int tid = threadIdx.x;
  const int l = tid & 63, w = tid >> 6;          // w = n-tile 0..3
  const int lane15 = l & 15, sub = l >> 4;
  const int bid = blockIdx.x;
  const int group = (bid & 7) >> 1;              // 0..3 (XCD-pair colocated)
  const int slice = (bid >> 3) * 2 + (bid & 1);  // 0..15

  // Wh slice -> LDS (rows r=0..63 <-> h = slice*64+r), swizzled 16B slots
  for (int i = 0; i < 24; ++i) {
    int s = i * 256 + tid;          // 0..6143
    int r = s / 96;
    int ks = 32 + (s - r * 96);     // kslot 32..127
    f16x8 v = *(const f16x8*)(WhT + (size_t)(slice * 64 + r) * 1024 + ks * 8);
    *(f16x8*)(WhL + r * 1536 + ((ks ^ (r & 7)) - 32) * 16) = v;
  }
  // kk = 0..7 B-fragments in registers (stationary all 512 steps)
  const int colL = slice * 64 + w * 16 + lane15; // this lane's output column
  f16x8 breg[8];
  {
    const f16* src = WhT + (size_t)colL * 1024 + sub * 8;
#pragma unroll
    for (int kk = 0; kk < 8; ++kk) breg[kk] = *(const f16x8*)(src + kk * 32);
  }
  const int rA = lane15, xA = rA & 7;
  const int rB = w * 16 + lane15, xB = rB & 7;
  const unsigned char* stLb = stL + rA * 2048;
  const unsigned char* whb  = WhL + rB * 1536;

  // staging: thread (p = tid>>4, q = tid&15) owns producer p's 8B chunk q
  const int p = tid >> 4, q = tid & 15;
  // packed-store constants (4 f16 cols per thread, row = lane15)
  const int c0s = slice * 64 + w * 16 + sub * 4;
  const int stoff = lane15 * 2048 + (((c0s >> 3) ^ (lane15 & 7)) << 4) + (c0s & 7) * 2;

  for (int t = 0; t < T_; ++t) {
    const char* ib = (const char*)sbuf + (size_t)(t & 1) * 131072 + group * 32768;
    char*       ob = (char*)sbuf + (size_t)((t + 1) & 1) * 131072 + group * 32768;

    // xp for this step (plain cached loads, issued before the poll)
    float xpv[4];
#pragma unroll
    for (int j = 0; j < 4; ++j)
      xpv[j] = (float)xph[(size_t)(t * 64 + group * 16 + sub * 4 + j) * 1024 + colL];

    // ---- tag-polled staging: each word self-validates via stolen LSB ----
    {
      u64 tmp[16];
      const char* src = ib + p * 128 + q * 8;
#pragma unroll
      for (int i = 0; i < 16; ++i) tmp[i] = ALD64(src + i * 2048);
      const u32 want = (u32)((t >> 1) & 1);
      for (;;) {
        u32 bad = 0;
#pragma unroll
        for (int i = 0; i < 16; ++i) bad |= ((u32)tmp[i] ^ want) & 1u;
        if (bad == 0) break;
#pragma unroll
        for (int i = 0; i < 16; ++i) tmp[i] = ALD64(src + i * 2048);
      }
#pragma unroll
      for (int i = 0; i < 16; ++i)
        *(u64*)(stL + i * 2048 + p * 128 + q * 8) = tmp[i];
    }
    __syncthreads();   // stL complete (every thread validated its words)

    f32x4 acc0 = {0.f,0.f,0.f,0.f}, acc1 = {0.f,0.f,0.f,0.f};
#pragma unroll
    for (int kk = 0; kk < 32; ++kk) {
      const int s = kk * 4 + sub;
      f16x8 a = *(const f16x8*)(stLb + ((s ^ xA) << 4));
      f16x8 b = (kk < 8) ? breg[kk]
                         : *(const f16x8*)(whb + (((s ^ xB) - 32) << 4));
      if (kk & 1) acc1 = __builtin_amdgcn_mfma_f32_16x16x32_f16(a, b, acc1, 0, 0, 0);
      else        acc0 = __builtin_amdgcn_mfma_f32_16x16x32_f16(a, b, acc0, 0, 0, 0);
    }

    if (t == T_ - 1) {
#pragma unroll
      for (int j = 0; j < 4; ++j) {
        const int r = sub * 4 + j;
        out[(size_t)(group * 16 + r) * 1024 + colL] =
            tanhf(acc0[j] + acc1[j] + xpv[j]);
      }
      break;
    }

    // transpose this wave's 16x16 fragment (4 rows x 1 col per lane ->
    // 1 row x 4 cols per lane) through the wave-local tbuf region
#pragma unroll
    for (int j = 0; j < 4; ++j) {
      f16 hv = (f16)tanhf(acc0[j] + acc1[j] + xpv[j]);
      *(f16*)(tbuf + (sub * 4 + j) * 136 + (w * 16 + lane15) * 2) = hv;
    }
    asm volatile("s_waitcnt lgkmcnt(0)" ::: "memory");
    {
      u64 packed = *(const u64*)(tbuf + lane15 * 136 + (w * 16 + sub * 4) * 2);
      // stolen tag bit: LSB of f16#0 <- ((t+1)>>1) & 1  (<=1 ulp on 1/4 elems)
      packed = (packed & ~1ull) | (u64)(((t + 1) >> 1) & 1);
      AST64(ob + stoff, packed);   // fire-and-forget: no drain, no flag
    }
    __syncthreads();   // all waves done reading stL before next staging
  }
}

// ---------------------------------------------------------------------------
extern "C" void kernel_launch(void* const* d_in, const int* in_sizes, int n_in,
                              void* d_out, int out_size, void* d_ws, size_t ws_size,
                              hipStream_t stream) {
  const float* x    = (const float*)d_in[0];
  const float* W    = (const float*)d_in[1];
  const float* bias = (const float*)d_in[2];
  float* out = (float*)d_out;
  char* w = (char*)d_ws;

  f16* xph = (f16*)(w + XPH_OFF);
  f16* WxT = (f16*)(w + WXT_OFF);
  f16* WhT = (f16*)(w + WHT_OFF);
  f16* sbuf = (f16*)(w + SBUF_OFF);

  // tag-aware image init: parity 0 = state0 (tag 0), parity 1 = tag 1
  k_init<<<dim3(128), dim3(256), 0, stream>>>((u64*)(w + SBUF_OFF));

  k_prep<<<dim3(48 * 32), dim3(256), 0, stream>>>(W, WxT, WhT);
  k_xproj<<<dim3(512), dim3(256), 0, stream>>>(x, WxT, bias, xph);
  k_rnn<<<dim3(64), dim3(256), 0, stream>>>(xph, WhT, sbuf, out);
}